// Round 6
// baseline (870.715 us; speedup 1.0000x reference)
//
#include <hip/hip_runtime.h>
#include <hip/hip_cooperative_groups.h>

namespace cg = cooperative_groups;

// B=16, D=16, H=288, W=512, L=17 (fixed by setup_inputs)
#define BB   16
#define DD   16
#define NN   (288*512)     // 147456 pixels/image
#define LL   17
#define TPB  256
#define NREP 16            // LDS table replicas (4 lanes/replica)

#define PB   72            // accum blocks/image -> grid 1152 (~4.5/CU resident)
#define QB   (NN/4/PB)     // 512 quads/block -> 8 pipeline iters of 64 lanes
#define VT   144           // var tiles/image, 1024 px each (256 quads)

#define FSCALE 32768.0f
#define INV_FSCALE (1.0f/32768.0f)
#define MW_STRIDE 320      // per-image means(289) + wl(17), padded
#define PUSH_OFF (BB*VT)   // push-term slots in vpart

// ws: part int[B][PB][289] | mw float[B][320] | vpart float[BB*VT + BB]
// No atomics; fixed fold order -> deterministic.

// ---------------------------------------------------------------------------
// Shared device bodies (fused kernel + fallback path)
// ---------------------------------------------------------------------------

__device__ __forceinline__ void accum_body(const float* __restrict__ emb,
                                           const int* __restrict__ seg,
                                           int* __restrict__ part,
                                           int* tab, int b, int sub) {
    const int tid  = threadIdx.x;
    const int dgrp = tid >> 6;          // wave owns channels 4*dgrp..+3
    const int j    = tid & 63;
    int* trep = tab + (j & (NREP - 1)) * 289;

    for (int i = tid; i < NREP * 289; i += TPB) tab[i] = 0;

    const float* embb = emb + (size_t)b * DD * NN;
    const int*   segb = seg + (size_t)b * NN;
    const float* r0 = embb + (size_t)(dgrp * 4 + 0) * NN;
    const float* r1 = embb + (size_t)(dgrp * 4 + 1) * NN;
    const float* r2 = embb + (size_t)(dgrp * 4 + 2) * NN;
    const float* r3 = embb + (size_t)(dgrp * 4 + 3) * NN;
    const int q0 = sub * QB;
    __syncthreads();

    // 2-stage software pipeline: iter i+1 loads issue before iter i's atomics.
    int n = (q0 + j) * 4;
    int4   s4 = *(const int4*)(segb + n);
    float4 e0 = *(const float4*)(r0 + n);
    float4 e1 = *(const float4*)(r1 + n);
    float4 e2 = *(const float4*)(r2 + n);
    float4 e3 = *(const float4*)(r3 + n);

#pragma unroll
    for (int it = 0; it < QB / 64; ++it) {
        int4 s4n = s4; float4 e0n = e0, e1n = e1, e2n = e2, e3n = e3;
        if (it + 1 < QB / 64) {
            const int nn_ = (q0 + (it + 1) * 64 + j) * 4;
            s4n = *(const int4*)(segb + nn_);
            e0n = *(const float4*)(r0 + nn_);
            e1n = *(const float4*)(r1 + nn_);
            e2n = *(const float4*)(r2 + nn_);
            e3n = *(const float4*)(r3 + nn_);
        }
        const int ch = dgrp * 4;
        // label 0 feeds only zero-weighted terms -> skip its traffic entirely.
        if (s4.x) {
            const int o0 = s4.x * 17 + ch;
            atomicAdd(trep + o0 + 0, __float2int_rn(e0.x * FSCALE));
            atomicAdd(trep + o0 + 1, __float2int_rn(e1.x * FSCALE));
            atomicAdd(trep + o0 + 2, __float2int_rn(e2.x * FSCALE));
            atomicAdd(trep + o0 + 3, __float2int_rn(e3.x * FSCALE));
            if (dgrp == 0) atomicAdd(trep + s4.x * 17 + 16, 1);
        }
        if (s4.y) {
            const int o1 = s4.y * 17 + ch;
            atomicAdd(trep + o1 + 0, __float2int_rn(e0.y * FSCALE));
            atomicAdd(trep + o1 + 1, __float2int_rn(e1.y * FSCALE));
            atomicAdd(trep + o1 + 2, __float2int_rn(e2.y * FSCALE));
            atomicAdd(trep + o1 + 3, __float2int_rn(e3.y * FSCALE));
            if (dgrp == 0) atomicAdd(trep + s4.y * 17 + 16, 1);
        }
        if (s4.z) {
            const int o2 = s4.z * 17 + ch;
            atomicAdd(trep + o2 + 0, __float2int_rn(e0.z * FSCALE));
            atomicAdd(trep + o2 + 1, __float2int_rn(e1.z * FSCALE));
            atomicAdd(trep + o2 + 2, __float2int_rn(e2.z * FSCALE));
            atomicAdd(trep + o2 + 3, __float2int_rn(e3.z * FSCALE));
            if (dgrp == 0) atomicAdd(trep + s4.z * 17 + 16, 1);
        }
        if (s4.w) {
            const int o3 = s4.w * 17 + ch;
            atomicAdd(trep + o3 + 0, __float2int_rn(e0.w * FSCALE));
            atomicAdd(trep + o3 + 1, __float2int_rn(e1.w * FSCALE));
            atomicAdd(trep + o3 + 2, __float2int_rn(e2.w * FSCALE));
            atomicAdd(trep + o3 + 3, __float2int_rn(e3.w * FSCALE));
            if (dgrp == 0) atomicAdd(trep + s4.w * 17 + 16, 1);
        }
        s4 = s4n; e0 = e0n; e1 = e1n; e2 = e2n; e3 = e3n;
    }
    __syncthreads();

    // plain coalesced partial stores (no global atomics)
    int* pout = part + ((size_t)b * PB + sub) * 289;
    for (int i = tid; i < 289; i += TPB) {
        int v = 0;
#pragma unroll
        for (int r = 0; r < NREP; ++r) v += tab[r * 289 + i];
        pout[i] = v;
    }
}

__device__ __forceinline__ void reduce_body(const int* __restrict__ part,
                                            float* __restrict__ mw,
                                            float* __restrict__ vpart,
                                            float* m /*289+17 floats*/,
                                            float* wsum, int b) {
    const int tid = threadIdx.x;
    float* wl = m + 289;
    for (int i = tid; i < 289; i += TPB) {
        const int* p = part + (size_t)b * PB * 289 + i;
        int s = 0;
#pragma unroll 8
        for (int k = 0; k < PB; ++k) s += p[(size_t)k * 289];
        m[i] = (i % 17 == 16) ? (float)s : (float)s * INV_FSCALE;
    }
    __syncthreads();
    for (int i = tid; i < 272; i += TPB) {
        const int l = i >> 4, d = i & 15;
        m[l * 17 + d] /= fmaxf(m[l * 17 + 16], 1.f);
    }
    __syncthreads();

    int nl = 0;
#pragma unroll
    for (int l = 1; l < LL; ++l) nl += (m[l * 17 + 16] > 0.f) ? 1 : 0;
    const float nlf = (float)nl;
    if (tid < LL) {
        const bool pres = (tid != 0) && (m[tid * 17 + 16] > 0.f);
        wl[tid] = pres ? 1.f / (fmaxf(m[tid * 17 + 16], 1.f) * fmaxf(nlf, 1.f) * (float)BB)
                       : 0.f;
    }
    __syncthreads();

    float push = 0.f;
    if (nl > 1) {
        for (int p = tid; p < 289; p += TPB) {
            const int i = p / 17, jj = p % 17;
            if (i != jj && i > 0 && jj > 0 && m[i*17+16] > 0.f && m[jj*17+16] > 0.f) {
                float ss = 0.f;
#pragma unroll
                for (int d = 0; d < DD; ++d) {
                    const float df = m[i*17+d] - m[jj*17+d];
                    ss += df * df;
                }
                const float u = fmaxf(1.5f - sqrtf(ss), 0.f);
                push += u * u;
            }
        }
    }
#pragma unroll
    for (int off = 32; off; off >>= 1) push += __shfl_down(push, off, 64);
    if ((tid & 63) == 0) wsum[tid >> 6] = push;
    __syncthreads();
    if (tid == 0) {
        const float tot = wsum[0] + wsum[1] + wsum[2] + wsum[3];
        vpart[PUSH_OFF + b] =
            (nl > 1) ? tot / (fmaxf(nlf * (nlf - 1.f), 1.f) * 2.f * (float)BB) : 0.f;
    }
    for (int i = tid; i < 289 + LL; i += TPB)
        mw[(size_t)b * MW_STRIDE + i] = (i < 289) ? m[i] : wl[i - 289];
}

// one var tile = 1024 px (256 quads); chunked 4-deep float4 preload keeps
// >=4 independent loads in flight per wave regardless of compiler mood.
__device__ __forceinline__ float var_tile(const float* __restrict__ embb,
                                          const int* __restrict__ segb,
                                          const float* md, int vt) {
    const int tid = threadIdx.x;
    const int n = vt * 1024 + tid * 4;
    const int4 sq = *(const int4*)(segb + n);
    const int o0 = sq.x * 17, o1 = sq.y * 17, o2 = sq.z * 17, o3 = sq.w * 17;
    float ss0 = 0.f, ss1 = 0.f, ss2 = 0.f, ss3 = 0.f;
#pragma unroll
    for (int dc = 0; dc < DD; dc += 4) {
        const float4 ea = *(const float4*)(embb + (size_t)(dc + 0) * NN + n);
        const float4 eb = *(const float4*)(embb + (size_t)(dc + 1) * NN + n);
        const float4 ec = *(const float4*)(embb + (size_t)(dc + 2) * NN + n);
        const float4 ed = *(const float4*)(embb + (size_t)(dc + 3) * NN + n);
        float d0, d1, d2, d3;
        d0 = ea.x - md[o0 + dc + 0]; ss0 += d0 * d0;
        d1 = ea.y - md[o1 + dc + 0]; ss1 += d1 * d1;
        d2 = ea.z - md[o2 + dc + 0]; ss2 += d2 * d2;
        d3 = ea.w - md[o3 + dc + 0]; ss3 += d3 * d3;
        d0 = eb.x - md[o0 + dc + 1]; ss0 += d0 * d0;
        d1 = eb.y - md[o1 + dc + 1]; ss1 += d1 * d1;
        d2 = eb.z - md[o2 + dc + 1]; ss2 += d2 * d2;
        d3 = eb.w - md[o3 + dc + 1]; ss3 += d3 * d3;
        d0 = ec.x - md[o0 + dc + 2]; ss0 += d0 * d0;
        d1 = ec.y - md[o1 + dc + 2]; ss1 += d1 * d1;
        d2 = ec.z - md[o2 + dc + 2]; ss2 += d2 * d2;
        d3 = ec.w - md[o3 + dc + 2]; ss3 += d3 * d3;
        d0 = ed.x - md[o0 + dc + 3]; ss0 += d0 * d0;
        d1 = ed.y - md[o1 + dc + 3]; ss1 += d1 * d1;
        d2 = ed.z - md[o2 + dc + 3]; ss2 += d2 * d2;
        d3 = ed.w - md[o3 + dc + 3]; ss3 += d3 * d3;
    }
    float accl = 0.f, t;
    t = fmaxf(sqrtf(fmaxf(ss0, 1e-12f)) - 0.5f, 0.f); accl += t * t * md[289 + sq.x];
    t = fmaxf(sqrtf(fmaxf(ss1, 1e-12f)) - 0.5f, 0.f); accl += t * t * md[289 + sq.y];
    t = fmaxf(sqrtf(fmaxf(ss2, 1e-12f)) - 0.5f, 0.f); accl += t * t * md[289 + sq.z];
    t = fmaxf(sqrtf(fmaxf(ss3, 1e-12f)) - 0.5f, 0.f); accl += t * t * md[289 + sq.w];
    return accl;
}

// ---------------------------------------------------------------------------
// Fused cooperative kernel (primary path)
// ---------------------------------------------------------------------------
__global__ __launch_bounds__(TPB, 5) void k_fused(const float* __restrict__ emb,
                                                  const int* __restrict__ seg,
                                                  int* __restrict__ part,
                                                  float* __restrict__ mw,
                                                  float* __restrict__ vpart,
                                                  float* __restrict__ out) {
    __shared__ int tab[NREP * 289];     // phase1 histogram; overlaid later
    __shared__ float wsum[TPB / 64];
    cg::grid_group grid = cg::this_grid();

    const int tid = threadIdx.x;
    const int b   = blockIdx.y;
    const int sub = blockIdx.x;

    accum_body(emb, seg, part, tab, b, sub);
    __threadfence();
    grid.sync();

    if (sub == 0) {
        reduce_body(part, mw, vpart, (float*)tab, wsum, b);
        __threadfence();
    }
    grid.sync();

    {   // var phase: 2 tiles per block (72 blocks x 2 = 144 tiles/image)
        float* md = (float*)tab;
        for (int i = tid; i < 306; i += TPB) md[i] = mw[(size_t)b * MW_STRIDE + i];
        __syncthreads();
        const float* embb = emb + (size_t)b * DD * NN;
        const int*   segb = seg + (size_t)b * NN;
        float accl = var_tile(embb, segb, md, sub * 2)
                   + var_tile(embb, segb, md, sub * 2 + 1);
#pragma unroll
        for (int off = 32; off; off >>= 1) accl += __shfl_down(accl, off, 64);
        if ((tid & 63) == 0) wsum[tid >> 6] = accl;
        __syncthreads();
        if (tid == 0)
            vpart[(size_t)b * PB + sub] = wsum[0] + wsum[1] + wsum[2] + wsum[3];
    }
    __threadfence();
    grid.sync();

    if (b == 0 && sub == 0) {
        float v = 0.f;
        for (int i = tid; i < BB * PB; i += TPB) v += vpart[i];
        if (tid < BB) v += vpart[PUSH_OFF + tid];
#pragma unroll
        for (int off = 32; off; off >>= 1) v += __shfl_down(v, off, 64);
        if ((tid & 63) == 0) wsum[tid >> 6] = v;
        __syncthreads();
        if (tid == 0) out[0] = wsum[0] + wsum[1] + wsum[2] + wsum[3];
    }
}

// ---------------------------------------------------------------------------
// Fallback path: 4 plain dispatches (round-3-verified structure)
// ---------------------------------------------------------------------------
__global__ __launch_bounds__(TPB) void k_accum(const float* __restrict__ emb,
                                               const int* __restrict__ seg,
                                               int* __restrict__ part) {
    __shared__ int tab[NREP * 289];
    accum_body(emb, seg, part, tab, blockIdx.y, blockIdx.x);
}

__global__ __launch_bounds__(TPB) void k_reduce(const int* __restrict__ part,
                                                float* __restrict__ mw,
                                                float* __restrict__ vpart) {
    __shared__ float m[289 + 17];
    __shared__ float wsum[TPB / 64];
    reduce_body(part, mw, vpart, m, wsum, blockIdx.x);
}

__global__ __launch_bounds__(TPB, 4) void k_var(const float* __restrict__ emb,
                                                const int* __restrict__ seg,
                                                const float* __restrict__ mw,
                                                float* __restrict__ vpart) {
    __shared__ float md[306];
    __shared__ float wsum[TPB / 64];
    const int tid = threadIdx.x, b = blockIdx.y;
    for (int i = tid; i < 306; i += TPB) md[i] = mw[(size_t)b * MW_STRIDE + i];
    __syncthreads();
    float accl = var_tile(emb + (size_t)b * DD * NN, seg + (size_t)b * NN,
                          md, blockIdx.x);
#pragma unroll
    for (int off = 32; off; off >>= 1) accl += __shfl_down(accl, off, 64);
    if ((tid & 63) == 0) wsum[tid >> 6] = accl;
    __syncthreads();
    if (tid == 0)
        vpart[(size_t)b * VT + blockIdx.x] = wsum[0] + wsum[1] + wsum[2] + wsum[3];
}

__global__ __launch_bounds__(TPB) void k_final(const float* __restrict__ vpart,
                                               float* __restrict__ out) {
    __shared__ float ws4[TPB / 64];
    float v = 0.f;
    for (int i = threadIdx.x; i < BB * VT + BB; i += TPB) v += vpart[i];
#pragma unroll
    for (int off = 32; off; off >>= 1) v += __shfl_down(v, off, 64);
    if ((threadIdx.x & 63) == 0) ws4[threadIdx.x >> 6] = v;
    __syncthreads();
    if (threadIdx.x == 0) out[0] = ws4[0] + ws4[1] + ws4[2] + ws4[3];
}

extern "C" void kernel_launch(void* const* d_in, const int* in_sizes, int n_in,
                              void* d_out, int out_size, void* d_ws, size_t ws_size,
                              hipStream_t stream) {
    const float* emb = (const float*)d_in[0];
    const int*   seg = (const int*)d_in[1];
    float* out = (float*)d_out;

    int*   part  = (int*)d_ws;                              // 16*72*289 ints
    float* mw    = (float*)(part + (size_t)BB * PB * 289);  // 16*320 floats
    float* vpart = mw + (size_t)BB * MW_STRIDE;             // 16*144+16 floats

    void* args[] = {(void*)&emb, (void*)&seg, (void*)&part,
                    (void*)&mw,  (void*)&vpart, (void*)&out};
    hipError_t err = hipLaunchCooperativeKernel((void*)k_fused, dim3(PB, BB),
                                                dim3(TPB), args, 0, stream);
    if (err != hipSuccess) {
        // cooperative launch rejected -> plain 4-dispatch path
        k_accum <<<dim3(PB, BB), TPB, 0, stream>>>(emb, seg, part);
        k_reduce<<<BB, TPB, 0, stream>>>(part, mw, vpart);
        k_var   <<<dim3(VT, BB), TPB, 0, stream>>>(emb, seg, mw, vpart);
        k_final <<<1, TPB, 0, stream>>>(vpart, out);
    }
}

// Round 7
// 245.192 us; speedup vs baseline: 3.5512x; 3.5512x over previous
//
#include <hip/hip_runtime.h>

// B=16, D=16, H=288, W=512, L=17 (fixed by setup_inputs)
#define BB   16
#define DD   16
#define NN   (288*512)     // 147456 pixels/image
#define LL   17
#define TPB  256
#define NREP 16            // LDS table replicas (4 lanes/replica)

#define PB   144           // accum blocks/image: 2304 blocks (8 resident/CU by LDS)
#define QB   (NN/4/PB)     // 256 quads/block -> 4 pipeline iters of 64 lanes
#define PBV  144           // var blocks/image: 1024 px/block one-shot

#define FSCALE 32768.0f
#define INV_FSCALE (1.0f/32768.0f)

// ws layout: acc int[B][289] | vpart float[B*PBV]
// Best-measured structure (242.6/243.6 us). Rounds 5/6 proved the cooperative
// fused alternative is 2-3.5x worse (grid.sync spin + capped per-phase TLP),
// and that ~150-200 us of the measured total is fixed harness overhead
// (k_fused dispatch 429/670 us vs totals 582/871 us).

__global__ __launch_bounds__(TPB) void k_accum(const float* __restrict__ emb,
                                               const int* __restrict__ seg,
                                               int* __restrict__ acc) {
    __shared__ int tab[NREP * 289];   // pad-17 rows: injective label->bank (gcd(17,32)=1)
    const int tid  = threadIdx.x;
    const int b    = blockIdx.y;
    const int blk  = blockIdx.x;
    const int dgrp = tid >> 6;        // wave owns channels 4*dgrp..+3 (wave-uniform)
    const int j    = tid & 63;
    int* trep = tab + (j & (NREP - 1)) * 289;

    for (int i = tid; i < NREP * 289; i += TPB) tab[i] = 0;

    const float* embb = emb + (size_t)b * DD * NN;
    const int*   segb = seg + (size_t)b * NN;
    const float* r0 = embb + (size_t)(dgrp * 4 + 0) * NN;
    const float* r1 = embb + (size_t)(dgrp * 4 + 1) * NN;
    const float* r2 = embb + (size_t)(dgrp * 4 + 2) * NN;
    const float* r3 = embb + (size_t)(dgrp * 4 + 3) * NN;
    const int q0 = blk * QB;
    __syncthreads();

    // 2-stage software pipeline: iter i+1 loads issue before iter i's atomics,
    // keeping ~10 vector loads in flight per wave.
    int n = (q0 + j) * 4;
    int4   s4 = *(const int4*)(segb + n);
    float4 e0 = *(const float4*)(r0 + n);
    float4 e1 = *(const float4*)(r1 + n);
    float4 e2 = *(const float4*)(r2 + n);
    float4 e3 = *(const float4*)(r3 + n);

#pragma unroll
    for (int it = 0; it < QB / 64; ++it) {
        int4 s4n = s4; float4 e0n = e0, e1n = e1, e2n = e2, e3n = e3;
        if (it + 1 < QB / 64) {
            const int nn_ = (q0 + (it + 1) * 64 + j) * 4;
            s4n = *(const int4*)(segb + nn_);
            e0n = *(const float4*)(r0 + nn_);
            e1n = *(const float4*)(r1 + nn_);
            e2n = *(const float4*)(r2 + nn_);
            e3n = *(const float4*)(r3 + nn_);
        }
        const int ch = dgrp * 4;
        // label 0 feeds only zero-weighted terms (wl[0]=0, present excludes 0)
        // -> skip its sums AND count entirely (~1/17 of LDS RMW traffic).
        // native ds_add_u32 (no return -> fire-and-forget), fixed-point 2^15
        if (s4.x) {
            const int o0 = s4.x * 17 + ch;
            atomicAdd(trep + o0 + 0, __float2int_rn(e0.x * FSCALE));
            atomicAdd(trep + o0 + 1, __float2int_rn(e1.x * FSCALE));
            atomicAdd(trep + o0 + 2, __float2int_rn(e2.x * FSCALE));
            atomicAdd(trep + o0 + 3, __float2int_rn(e3.x * FSCALE));
            if (dgrp == 0) atomicAdd(trep + s4.x * 17 + 16, 1);
        }
        if (s4.y) {
            const int o1 = s4.y * 17 + ch;
            atomicAdd(trep + o1 + 0, __float2int_rn(e0.y * FSCALE));
            atomicAdd(trep + o1 + 1, __float2int_rn(e1.y * FSCALE));
            atomicAdd(trep + o1 + 2, __float2int_rn(e2.y * FSCALE));
            atomicAdd(trep + o1 + 3, __float2int_rn(e3.y * FSCALE));
            if (dgrp == 0) atomicAdd(trep + s4.y * 17 + 16, 1);
        }
        if (s4.z) {
            const int o2 = s4.z * 17 + ch;
            atomicAdd(trep + o2 + 0, __float2int_rn(e0.z * FSCALE));
            atomicAdd(trep + o2 + 1, __float2int_rn(e1.z * FSCALE));
            atomicAdd(trep + o2 + 2, __float2int_rn(e2.z * FSCALE));
            atomicAdd(trep + o2 + 3, __float2int_rn(e3.z * FSCALE));
            if (dgrp == 0) atomicAdd(trep + s4.z * 17 + 16, 1);
        }
        if (s4.w) {
            const int o3 = s4.w * 17 + ch;
            atomicAdd(trep + o3 + 0, __float2int_rn(e0.w * FSCALE));
            atomicAdd(trep + o3 + 1, __float2int_rn(e1.w * FSCALE));
            atomicAdd(trep + o3 + 2, __float2int_rn(e2.w * FSCALE));
            atomicAdd(trep + o3 + 3, __float2int_rn(e3.w * FSCALE));
            if (dgrp == 0) atomicAdd(trep + s4.w * 17 + 16, 1);
        }
        s4 = s4n; e0 = e0n; e1 = e1n; e2 = e2n; e3 = e3n;
    }
    __syncthreads();

    for (int i = tid; i < 289; i += TPB) {
        int v = 0;
#pragma unroll
        for (int r = 0; r < NREP; ++r) v += tab[r * 289 + i];
        atomicAdd(acc + b * 289 + i, v);   // native global int atomic, 19 lines/img
    }
}

// __launch_bounds__(256, 4): ~128 VGPR cap; chunked 4-deep float4 preload keeps
// >=4 independent loads in flight per wave regardless of regalloc mood.
// (VGPR=40 fully-serial version measured 107us, VALUBusy 5%, 1.5 TB/s.)
__global__ __launch_bounds__(TPB, 4) void k_var(const float* __restrict__ emb,
                                                const int* __restrict__ seg,
                                                const int* __restrict__ acc,
                                                float* __restrict__ vpart) {
    __shared__ float m[289];     // padded [17][17]: conflict-free random lookups
    __shared__ float wl[17];
    __shared__ float wsum[TPB / 64];
    const int tid = threadIdx.x;
    const int b = blockIdx.y;

    for (int i = tid; i < 289; i += TPB) {
        const int raw = acc[b * 289 + i];
        m[i] = (i % 17 == 16) ? (float)raw : (float)raw * INV_FSCALE;
    }
    __syncthreads();
    for (int i = tid; i < 272; i += TPB) {
        const int l = i >> 4, d = i & 15;
        m[l * 17 + d] /= fmaxf(m[l * 17 + 16], 1.f);
    }
    __syncthreads();

    int nl = 0;
#pragma unroll
    for (int l = 1; l < LL; ++l) nl += (m[l * 17 + 16] > 0.f) ? 1 : 0;
    const float nlf = (float)nl;
    if (tid < LL) {
        const bool pres = (tid != 0) && (m[tid * 17 + 16] > 0.f);
        wl[tid] = pres ? 1.f / (fmaxf(m[tid * 17 + 16], 1.f) * fmaxf(nlf, 1.f) * (float)BB)
                       : 0.f;
    }
    __syncthreads();

    const float* embb = emb + (size_t)b * DD * NN;
    const int*   segb = seg + (size_t)b * NN;

    const int n = blockIdx.x * (TPB * 4) + tid * 4;   // 144*1024 = NN exactly
    const int4 sq = *(const int4*)(segb + n);
    const int o0 = sq.x * 17, o1 = sq.y * 17, o2 = sq.z * 17, o3 = sq.w * 17;
    float ss0 = 0.f, ss1 = 0.f, ss2 = 0.f, ss3 = 0.f;
#pragma unroll
    for (int dc = 0; dc < DD; dc += 4) {
        const float4 ea = *(const float4*)(embb + (size_t)(dc + 0) * NN + n);
        const float4 eb = *(const float4*)(embb + (size_t)(dc + 1) * NN + n);
        const float4 ec = *(const float4*)(embb + (size_t)(dc + 2) * NN + n);
        const float4 ed = *(const float4*)(embb + (size_t)(dc + 3) * NN + n);
        float d0, d1, d2, d3;
        d0 = ea.x - m[o0 + dc + 0]; ss0 += d0 * d0;
        d1 = ea.y - m[o1 + dc + 0]; ss1 += d1 * d1;
        d2 = ea.z - m[o2 + dc + 0]; ss2 += d2 * d2;
        d3 = ea.w - m[o3 + dc + 0]; ss3 += d3 * d3;
        d0 = eb.x - m[o0 + dc + 1]; ss0 += d0 * d0;
        d1 = eb.y - m[o1 + dc + 1]; ss1 += d1 * d1;
        d2 = eb.z - m[o2 + dc + 1]; ss2 += d2 * d2;
        d3 = eb.w - m[o3 + dc + 1]; ss3 += d3 * d3;
        d0 = ec.x - m[o0 + dc + 2]; ss0 += d0 * d0;
        d1 = ec.y - m[o1 + dc + 2]; ss1 += d1 * d1;
        d2 = ec.z - m[o2 + dc + 2]; ss2 += d2 * d2;
        d3 = ec.w - m[o3 + dc + 2]; ss3 += d3 * d3;
        d0 = ed.x - m[o0 + dc + 3]; ss0 += d0 * d0;
        d1 = ed.y - m[o1 + dc + 3]; ss1 += d1 * d1;
        d2 = ed.z - m[o2 + dc + 3]; ss2 += d2 * d2;
        d3 = ed.w - m[o3 + dc + 3]; ss3 += d3 * d3;
    }
    float accl = 0.f, t;
    t = fmaxf(sqrtf(fmaxf(ss0, 1e-12f)) - 0.5f, 0.f); accl += t * t * wl[sq.x];
    t = fmaxf(sqrtf(fmaxf(ss1, 1e-12f)) - 0.5f, 0.f); accl += t * t * wl[sq.y];
    t = fmaxf(sqrtf(fmaxf(ss2, 1e-12f)) - 0.5f, 0.f); accl += t * t * wl[sq.z];
    t = fmaxf(sqrtf(fmaxf(ss3, 1e-12f)) - 0.5f, 0.f); accl += t * t * wl[sq.w];

    // push (distance) term, once per image, folded into block-0's partial
    if (blockIdx.x == 0 && nl > 1) {
        float push = 0.f;
        for (int p = tid; p < 289; p += TPB) {
            const int i = p / 17, jj = p % 17;
            if (i != jj && i > 0 && jj > 0 && m[i*17+16] > 0.f && m[jj*17+16] > 0.f) {
                float ss = 0.f;
#pragma unroll
                for (int d = 0; d < DD; ++d) {
                    const float df = m[i*17+d] - m[jj*17+d];
                    ss += df * df;
                }
                const float u = fmaxf(1.5f - sqrtf(ss), 0.f);
                push += u * u;
            }
        }
        accl += push / (fmaxf(nlf * (nlf - 1.f), 1.f) * 2.f * (float)BB);
    }

#pragma unroll
    for (int off = 32; off; off >>= 1) accl += __shfl_down(accl, off, 64);
    if ((tid & 63) == 0) wsum[tid >> 6] = accl;
    __syncthreads();
    if (tid == 0)
        vpart[(size_t)b * PBV + blockIdx.x] = wsum[0] + wsum[1] + wsum[2] + wsum[3];
}

__global__ __launch_bounds__(TPB) void k_final(const float* __restrict__ vpart,
                                               float* __restrict__ out) {
    __shared__ float ws4[TPB / 64];
    float v = 0.f;
    for (int i = threadIdx.x; i < BB * PBV; i += TPB) v += vpart[i];
#pragma unroll
    for (int off = 32; off; off >>= 1) v += __shfl_down(v, off, 64);
    if ((threadIdx.x & 63) == 0) ws4[threadIdx.x >> 6] = v;
    __syncthreads();
    if (threadIdx.x == 0) out[0] = ws4[0] + ws4[1] + ws4[2] + ws4[3];
}

extern "C" void kernel_launch(void* const* d_in, const int* in_sizes, int n_in,
                              void* d_out, int out_size, void* d_ws, size_t ws_size,
                              hipStream_t stream) {
    const float* emb = (const float*)d_in[0];
    const int*   seg = (const int*)d_in[1];
    float* out = (float*)d_out;

    int*   acc   = (int*)d_ws;                 // 16*289 ints
    float* vpart = (float*)(acc + BB * 289);   // BB*PBV floats

    hipMemsetAsync(acc, 0, (size_t)BB * 289 * sizeof(int), stream);

    k_accum<<<dim3(PB, BB), TPB, 0, stream>>>(emb, seg, acc);
    k_var  <<<dim3(PBV, BB), TPB, 0, stream>>>(emb, seg, acc, vpart);
    k_final<<<1, TPB, 0, stream>>>(vpart, out);
}